// Round 2
// baseline (489.215 us; speedup 1.0000x reference)
//
#include <hip/hip_runtime.h>

#define B_ 8
#define T_ 4096
#define W_ 1024
#define H_ 8
#define BW_ 128
#define M_ 128          // timesteps per chunk
#define NC_ 32          // chunks per sequence (T_/M_)
#define XS 136          // LDS row stride (halves) for X/W tiles: 272B rows, 2-way banks max
#define PS 132          // LDS row stride (words) for packed la|nx tile

typedef __attribute__((ext_vector_type(8))) short bf16x8;
typedef __attribute__((ext_vector_type(4))) float f32x4;

__device__ __forceinline__ float bf2f(unsigned short u) {
    return __uint_as_float(((unsigned)u) << 16);
}
__device__ __forceinline__ unsigned short f2bf(float f) {
    unsigned u = __float_as_uint(f);
    u += 0x7fffu + ((u >> 16) & 1u);       // round-nearest-even
    return (unsigned short)(u >> 16);
}
__device__ __forceinline__ unsigned short f2h_bits(float f) {
    union { _Float16 h; unsigned short u; } cv;
    cv.h = (_Float16)f;
    return cv.u;
}
__device__ __forceinline__ float h2f(unsigned short u) {
    union { _Float16 h; unsigned short u; } cv;
    cv.u = u;
    return (float)cv.h;
}
__device__ __forceinline__ float sigmoidf_(float z) {
    return 1.0f / (1.0f + __expf(-z));
}

// ---------------- prep: fp32 weights -> transposed bf16 [h][j][i] in ws; cj = -8*softplus(a_param)
__global__ __launch_bounds__(256) void prep_kernel(
    const float* __restrict__ w_in, const float* __restrict__ w_a,
    const float* __restrict__ a_param,
    unsigned short* __restrict__ wt_in, unsigned short* __restrict__ wt_a,
    float* __restrict__ cj)
{
    int gid = blockIdx.x * 256 + threadIdx.x;     // 0..32767
    if (gid < W_) {
        float ap = a_param[gid];
        cj[gid] = -8.0f * log1pf(__expf(ap));     // a_param in [-6.9,-2.2]: safe
    }
    int mat  = gid >> 14;          // 0: w_in, 1: w_a
    int rem  = gid & 16383;
    int hh   = rem >> 11;          // head
    int r2   = rem & 2047;
    int seg  = r2 >> 7;            // i-segment (8 elems)
    int jrow = r2 & 127;           // output row j (low bits -> coalesced fp32 reads)
    const float* src = (mat ? w_a : w_in) + hh * BW_ * BW_;
    unsigned short* dst = (mat ? wt_a : wt_in) + hh * BW_ * BW_;
    unsigned short tmp[8] __attribute__((aligned(16)));
    #pragma unroll
    for (int k = 0; k < 8; ++k) tmp[k] = f2bf(src[(seg * 8 + k) * BW_ + jrow]);
    *(uint4*)(dst + jrow * BW_ + seg * 8) = *(const uint4*)tmp;
}

// ---------------- K2: sequential scan over chunk aggregates -> exclusive carries
__global__ __launch_bounds__(256) void carry_scan(
    const float* __restrict__ aggA, const float* __restrict__ aggE, float* __restrict__ carry)
{
    int g = blockIdx.x * 256 + threadIdx.x;   // 0..8191
    int s = g >> 7, j = g & 127;
    float hh = 0.0f;
    for (int c = 0; c < NC_; ++c) {
        size_t idx = ((size_t)s * NC_ + c) * BW_ + j;
        carry[idx] = hh;                       // state BEFORE chunk c
        hh = fmaf(aggA[idx], hh, aggE[idx]);
    }
}

// ---------------- main: gates (MFMA) + elementwise + chunk scan
// FINAL=false: write per-chunk aggregates (A, E).  FINAL=true: read carry, write y.
template<bool FINAL>
__global__ __launch_bounds__(512, 2) void rg_main(
    const float* __restrict__ x,
    const unsigned short* __restrict__ wt_in,
    const unsigned short* __restrict__ wt_a,
    const float* __restrict__ b_in,
    const float* __restrict__ b_a,
    const float* __restrict__ cj,
    float* __restrict__ aggA, float* __restrict__ aggE,
    const float* __restrict__ carry,
    float* __restrict__ y)
{
    __shared__ alignas(16) unsigned short Xs[M_ * XS];    // 34816 B  (x tile [t][i], bf16)
    __shared__ alignas(16) unsigned short Wsh[BW_ * XS];  // 34816 B  (Wt tile [j][i], bf16)
    __shared__ unsigned int Ps[M_ * PS];                  // 67584 B  (fp16 log_a << 16 | bf16 norm_x, [t][j])
    __shared__ float cj_s[BW_], ba_s[BW_], bi_s[BW_];
    __shared__ float qA[4 * BW_], qE[4 * BW_], qin[4 * BW_];

    const int tid = threadIdx.x;
    const int bid = blockIdx.x;
    const int c = bid & (NC_ - 1);
    const int s = bid >> 5;
    const int b = s >> 3;
    const int h = s & 7;
    const int t0 = c * M_;

    const float* xg = x + ((size_t)b * T_ + t0) * W_ + h * BW_;
    const unsigned short* wag = wt_a + h * BW_ * BW_;
    const unsigned short* wig = wt_in + h * BW_ * BW_;

    // stage X tile (fp32 -> bf16)
    #pragma unroll
    for (int r = 0; r < 8; ++r) {
        int u = tid + r * 512;         // 0..4095
        int t = u >> 5, sg = u & 31;   // 4 floats per sg
        const float4 v = *(const float4*)(xg + (size_t)t * W_ + sg * 4);
        ushort4 hv;
        hv.x = f2bf(v.x); hv.y = f2bf(v.y); hv.z = f2bf(v.z); hv.w = f2bf(v.w);
        *(ushort4*)&Xs[t * XS + sg * 4] = hv;
    }
    // stage Wt_a tile; prefetch Wt_in to registers (both already bf16)
    uint4 wreg[4];
    #pragma unroll
    for (int r = 0; r < 4; ++r) {
        int u = tid + r * 512;
        int t = u >> 4, seg = u & 15;
        *(uint4*)&Wsh[t * XS + seg * 8] = *(const uint4*)(wag + t * BW_ + seg * 8);
        wreg[r] = *(const uint4*)(wig + t * BW_ + seg * 8);
    }
    if (tid < BW_) {
        cj_s[tid] = cj[h * BW_ + tid];
        ba_s[tid] = b_a[h * BW_ + tid];
        bi_s[tid] = b_in[h * BW_ + tid];
    }
    __syncthreads();

    const int wave = tid >> 6;
    const int lane = tid & 63;
    const int q  = lane >> 4;
    const int cl = lane & 15;
    const int mw = wave >> 1;       // 0..3: 32-row group
    const int nw = wave & 1;        // 0..1: 64-col half

    f32x4 zero4 = {0.0f, 0.0f, 0.0f, 0.0f};
    f32x4 acc_a[2][4], acc_x[2][4];
    #pragma unroll
    for (int mt = 0; mt < 2; ++mt)
        #pragma unroll
        for (int nt = 0; nt < 4; ++nt) { acc_a[mt][nt] = zero4; acc_x[mt][nt] = zero4; }

    // gate_a pass; keep A-fragments in registers for reuse in gate_x pass
    bf16x8 af[2][4];
    #pragma unroll
    for (int kk = 0; kk < 4; ++kk) {
        #pragma unroll
        for (int mt = 0; mt < 2; ++mt)
            af[mt][kk] = *(const bf16x8*)&Xs[(mw * 32 + mt * 16 + cl) * XS + kk * 32 + q * 8];
        #pragma unroll
        for (int nt = 0; nt < 4; ++nt) {
            bf16x8 bf = *(const bf16x8*)&Wsh[(nw * 64 + nt * 16 + cl) * XS + kk * 32 + q * 8];
            #pragma unroll
            for (int mt = 0; mt < 2; ++mt)
                acc_a[mt][nt] = __builtin_amdgcn_mfma_f32_16x16x32_bf16(af[mt][kk], bf, acc_a[mt][nt], 0, 0, 0);
        }
    }
    __syncthreads();
    #pragma unroll
    for (int r = 0; r < 4; ++r) {
        int u = tid + r * 512;
        int t = u >> 4, seg = u & 15;
        *(uint4*)&Wsh[t * XS + seg * 8] = wreg[r];
    }
    __syncthreads();
    // gate_x pass
    #pragma unroll
    for (int kk = 0; kk < 4; ++kk) {
        #pragma unroll
        for (int nt = 0; nt < 4; ++nt) {
            bf16x8 bf = *(const bf16x8*)&Wsh[(nw * 64 + nt * 16 + cl) * XS + kk * 32 + q * 8];
            #pragma unroll
            for (int mt = 0; mt < 2; ++mt)
                acc_x[mt][nt] = __builtin_amdgcn_mfma_f32_16x16x32_bf16(af[mt][kk], bf, acc_x[mt][nt], 0, 0, 0);
        }
    }

    // elementwise: sigmoid gates -> log_a (fp16) | norm_x (bf16) packed into Ps[t][j]
    #pragma unroll
    for (int mt = 0; mt < 2; ++mt) {
        #pragma unroll
        for (int nt = 0; nt < 4; ++nt) {
            int j = nw * 64 + nt * 16 + cl;
            float cjv = cj_s[j], bav = ba_s[j], biv = bi_s[j];
            #pragma unroll
            for (int r = 0; r < 4; ++r) {
                int tl = mw * 32 + mt * 16 + q * 4 + r;          // C/D layout: row = q*4 + reg
                float la = cjv * sigmoidf_(acc_a[mt][nt][r] + bav);   // log_a <= 0
                float gx = sigmoidf_(acc_x[mt][nt][r] + biv);
                float xv = bf2f(Xs[tl * XS + j]);
                float mult = sqrtf(fmaxf(-expm1f(2.0f * la), 0.0f));
                if (t0 + tl == 0) { mult = 1.0f; la = -1e30f; }  // reset at global t=0: a=0, mult=1
                float nx = xv * gx * mult;
                Ps[tl * PS + j] = ((unsigned)f2h_bits(la) << 16) | (unsigned)f2bf(nx);
            }
        }
    }
    __syncthreads();

    // 4-way parallel intra-chunk scan: quarter qq handles rows [32qq, 32qq+32)
    const int jq = tid & 127;
    const int qq = tid >> 7;
    {
        float A = 1.0f, E = 0.0f;
        #pragma unroll 4
        for (int i = 0; i < 32; ++i) {
            unsigned pw = Ps[(qq * 32 + i) * PS + jq];
            float a  = __expf(h2f((unsigned short)(pw >> 16)));
            float nx = bf2f((unsigned short)(pw & 0xffffu));
            E = fmaf(a, E, nx);
            A *= a;
        }
        qA[qq * BW_ + jq] = A;
        qE[qq * BW_ + jq] = E;
    }
    __syncthreads();

    if (!FINAL) {
        if (tid < BW_) {   // combine quarters: chunk aggregate (A_tot, E_tot)
            float At = qA[tid], Et = qE[tid];
            #pragma unroll
            for (int qi = 1; qi < 4; ++qi) {
                float Aq = qA[qi * BW_ + tid], Eq = qE[qi * BW_ + tid];
                Et = fmaf(Aq, Et, Eq);
                At *= Aq;
            }
            size_t idx = ((size_t)s * NC_ + c) * BW_ + tid;
            aggA[idx] = At;
            aggE[idx] = Et;
        }
    } else {
        if (tid < BW_) {   // quarter carry-ins from chunk carry
            float hh = carry[((size_t)s * NC_ + c) * BW_ + tid];
            qin[tid] = hh;
            #pragma unroll
            for (int qi = 1; qi < 4; ++qi) {
                hh = fmaf(qA[(qi - 1) * BW_ + tid], hh, qE[(qi - 1) * BW_ + tid]);
                qin[qi * BW_ + tid] = hh;
            }
        }
        __syncthreads();
        float* yg = y + ((size_t)b * T_ + t0) * W_ + h * BW_ + jq;
        float hcur = qin[qq * BW_ + jq];
        #pragma unroll 4
        for (int i = 0; i < 32; ++i) {
            int t = qq * 32 + i;
            unsigned pw = Ps[t * PS + jq];
            float a  = __expf(h2f((unsigned short)(pw >> 16)));
            float nx = bf2f((unsigned short)(pw & 0xffffu));
            hcur = fmaf(a, hcur, nx);
            yg[(size_t)t * W_] = hcur;     // coalesced across jq lanes
        }
    }
}

extern "C" void kernel_launch(void* const* d_in, const int* in_sizes, int n_in,
                              void* d_out, int out_size, void* d_ws, size_t ws_size,
                              hipStream_t stream)
{
    const float* x     = (const float*)d_in[0];
    const float* w_in  = (const float*)d_in[1];
    const float* b_in  = (const float*)d_in[2];
    const float* w_a   = (const float*)d_in[3];
    const float* b_a   = (const float*)d_in[4];
    const float* a_par = (const float*)d_in[5];
    float* y = (float*)d_out;

    char* ws = (char*)d_ws;
    // ws layout (bytes): Wt_in 0..256K, Wt_a 256K..512K, cj 512K..516K,
    // aggA, aggE, carry: 1 MB each
    unsigned short* wt_in = (unsigned short*)(ws);
    unsigned short* wt_a  = (unsigned short*)(ws + 262144);
    float* cj    = (float*)(ws + 524288);
    float* aggA  = (float*)(ws + 528384);
    float* aggE  = (float*)(ws + 1576960);
    float* carry = (float*)(ws + 2625536);
    if (ws_size < 3674112) return;   // insufficient scratch (not expected)

    prep_kernel<<<dim3(128), dim3(256), 0, stream>>>(w_in, w_a, a_par, wt_in, wt_a, cj);
    rg_main<false><<<dim3(2048), dim3(512), 0, stream>>>(
        x, wt_in, wt_a, b_in, b_a, cj, aggA, aggE, (const float*)nullptr, (float*)nullptr);
    carry_scan<<<dim3(32), dim3(256), 0, stream>>>(aggA, aggE, carry);
    rg_main<true><<<dim3(2048), dim3(512), 0, stream>>>(
        x, wt_in, wt_a, b_in, b_a, cj, aggA, aggE, carry, y);
}

// Round 3
// 438.646 us; speedup vs baseline: 1.1153x; 1.1153x over previous
//
#include <hip/hip_runtime.h>

#define B_ 8
#define T_ 4096
#define W_ 1024
#define H_ 8
#define BW_ 128
#define M_ 128          // timesteps per chunk
#define NC_ 32          // chunks per sequence (T_/M_)
#define XS 136          // LDS row stride (halves): 272B rows
#define NG_ 32          // 4-step groups per chunk
#define NS_ 8           // 16-step segments per chunk

typedef __attribute__((ext_vector_type(8))) short bf16x8;
typedef __attribute__((ext_vector_type(4))) float f32x4;

__device__ __forceinline__ float bf2f(unsigned short u) {
    return __uint_as_float(((unsigned)u) << 16);
}
__device__ __forceinline__ unsigned short f2bf(float f) {
    unsigned u = __float_as_uint(f);
    u += 0x7fffu + ((u >> 16) & 1u);       // round-nearest-even
    return (unsigned short)(u >> 16);
}
__device__ __forceinline__ unsigned short f2h_bits(float f) {
    union { _Float16 h; unsigned short u; } cv;
    cv.h = (_Float16)f;
    return cv.u;
}
__device__ __forceinline__ float h2f(unsigned short u) {
    union { _Float16 h; unsigned short u; } cv;
    cv.u = u;
    return (float)cv.h;
}
__device__ __forceinline__ float sigmoidf_(float z) {
    return 1.0f / (1.0f + __expf(-z));
}

// ---------------- prep: fp32 weights -> transposed bf16 [h][j][i] in ws; cj = -8*softplus(a_param)
__global__ __launch_bounds__(256) void prep_kernel(
    const float* __restrict__ w_in, const float* __restrict__ w_a,
    const float* __restrict__ a_param,
    unsigned short* __restrict__ wt_in, unsigned short* __restrict__ wt_a,
    float* __restrict__ cj)
{
    int gid = blockIdx.x * 256 + threadIdx.x;     // 0..32767
    if (gid < W_) {
        float ap = a_param[gid];
        cj[gid] = -8.0f * log1pf(__expf(ap));
    }
    int mat  = gid >> 14;          // 0: w_in, 1: w_a
    int rem  = gid & 16383;
    int hh   = rem >> 11;          // head
    int r2   = rem & 2047;
    int seg  = r2 >> 7;            // i-segment (8 elems)
    int jrow = r2 & 127;           // output row j (low bits -> coalesced fp32 reads)
    const float* src = (mat ? w_a : w_in) + hh * BW_ * BW_;
    unsigned short* dst = (mat ? wt_a : wt_in) + hh * BW_ * BW_;
    unsigned short tmp[8] __attribute__((aligned(16)));
    #pragma unroll
    for (int k = 0; k < 8; ++k) tmp[k] = f2bf(src[(seg * 8 + k) * BW_ + jrow]);
    *(uint4*)(dst + jrow * BW_ + seg * 8) = *(const uint4*)tmp;
}

// ---------------- K2: sequential scan over chunk aggregates -> exclusive carries
__global__ __launch_bounds__(256) void carry_scan(
    const float* __restrict__ aggA, const float* __restrict__ aggE, float* __restrict__ carry)
{
    int g = blockIdx.x * 256 + threadIdx.x;   // 0..8191
    int s = g >> 7, j = g & 127;
    float hh = 0.0f;
    for (int c = 0; c < NC_; ++c) {
        size_t idx = ((size_t)s * NC_ + c) * BW_ + j;
        carry[idx] = hh;                       // state BEFORE chunk c
        hh = fmaf(aggA[idx], hh, aggE[idx]);
    }
}

// ---------------- main: gates (MFMA) + elementwise + hierarchical chunk scan
// FINAL=false: write per-chunk aggregates (A, E).  FINAL=true: read carry, write y.
template<bool FINAL>
__global__ __launch_bounds__(1024, 4) void rg_main(
    const float* __restrict__ x,
    const unsigned short* __restrict__ wt_in,
    const unsigned short* __restrict__ wt_a,
    const float* __restrict__ b_in,
    const float* __restrict__ b_a,
    const float* __restrict__ cj,
    float* __restrict__ aggA, float* __restrict__ aggE,
    const float* __restrict__ carry,
    float* __restrict__ y)
{
    __shared__ alignas(16) unsigned short Xs[M_ * XS];    // 34816 B: x bf16, overwritten with nx (FINAL)
    __shared__ alignas(16) unsigned short Ah[M_ * XS];    // 34816 B: a fp16 (FINAL replay)
    __shared__ alignas(16) unsigned short Wsh[BW_ * XS];  // 34816 B: Wt bf16
    __shared__ float2 G[NG_ * BW_];                       // 32768 B: 4-step (A,E) aggregates
    __shared__ float2 S2[NS_ * BW_];                      //  8192 B: 16-step (A,E) aggregates
    __shared__ float qin[NS_ * BW_];                      //  4096 B: segment carry-ins
    __shared__ float cj_s[BW_], ba_s[BW_], bi_s[BW_];

    const int tid = threadIdx.x;
    const int bid = blockIdx.x;
    const int c = bid & (NC_ - 1);
    const int s = bid >> 5;
    const int b = s >> 3;
    const int h = s & 7;
    const int t0 = c * M_;

    const float* xg = x + ((size_t)b * T_ + t0) * W_ + h * BW_;
    const unsigned short* wag = wt_a + h * BW_ * BW_;
    const unsigned short* wig = wt_in + h * BW_ * BW_;

    // stage X tile (fp32 -> bf16)
    #pragma unroll
    for (int r = 0; r < 4; ++r) {
        int u = tid + r * 1024;        // 0..4095
        int t = u >> 5, sg = u & 31;   // 4 floats per sg
        const float4 v = *(const float4*)(xg + (size_t)t * W_ + sg * 4);
        ushort4 hv;
        hv.x = f2bf(v.x); hv.y = f2bf(v.y); hv.z = f2bf(v.z); hv.w = f2bf(v.w);
        *(ushort4*)&Xs[t * XS + sg * 4] = hv;
    }
    // stage Wt_a tile; prefetch Wt_in to registers (both already bf16)
    uint4 wreg[2];
    #pragma unroll
    for (int r = 0; r < 2; ++r) {
        int u = tid + r * 1024;
        int t = u >> 4, seg = u & 15;
        *(uint4*)&Wsh[t * XS + seg * 8] = *(const uint4*)(wag + t * BW_ + seg * 8);
        wreg[r] = *(const uint4*)(wig + t * BW_ + seg * 8);
    }
    if (tid < BW_) {
        cj_s[tid] = cj[h * BW_ + tid];
        ba_s[tid] = b_a[h * BW_ + tid];
        bi_s[tid] = b_in[h * BW_ + tid];
    }
    __syncthreads();

    const int wave = tid >> 6;
    const int lane = tid & 63;
    const int q  = lane >> 4;
    const int cl = lane & 15;
    const int mw = wave >> 1;       // 0..7: 16-row group
    const int nw = wave & 1;        // 0..1: 64-col half

    f32x4 zero4 = {0.0f, 0.0f, 0.0f, 0.0f};
    f32x4 acc_a[4], acc_x[4];
    #pragma unroll
    for (int nt = 0; nt < 4; ++nt) { acc_a[nt] = zero4; acc_x[nt] = zero4; }

    // gate_a pass; keep A-fragments in registers for reuse in gate_x pass
    bf16x8 af[4];
    #pragma unroll
    for (int kk = 0; kk < 4; ++kk) {
        af[kk] = *(const bf16x8*)&Xs[(mw * 16 + cl) * XS + kk * 32 + q * 8];
        #pragma unroll
        for (int nt = 0; nt < 4; ++nt) {
            bf16x8 bf = *(const bf16x8*)&Wsh[(nw * 64 + nt * 16 + cl) * XS + kk * 32 + q * 8];
            acc_a[nt] = __builtin_amdgcn_mfma_f32_16x16x32_bf16(af[kk], bf, acc_a[nt], 0, 0, 0);
        }
    }
    __syncthreads();
    #pragma unroll
    for (int r = 0; r < 2; ++r) {
        int u = tid + r * 1024;
        int t = u >> 4, seg = u & 15;
        *(uint4*)&Wsh[t * XS + seg * 8] = wreg[r];
    }
    __syncthreads();
    // gate_x pass
    #pragma unroll
    for (int kk = 0; kk < 4; ++kk) {
        #pragma unroll
        for (int nt = 0; nt < 4; ++nt) {
            bf16x8 bf = *(const bf16x8*)&Wsh[(nw * 64 + nt * 16 + cl) * XS + kk * 32 + q * 8];
            acc_x[nt] = __builtin_amdgcn_mfma_f32_16x16x32_bf16(af[kk], bf, acc_x[nt], 0, 0, 0);
        }
    }

    // elementwise: a = exp(cj*sigmoid), nx = x*gx*sqrt(1-a^2); 4-step aggregates in registers
    #pragma unroll
    for (int nt = 0; nt < 4; ++nt) {
        int j = nw * 64 + nt * 16 + cl;
        float cjv = cj_s[j], bav = ba_s[j], biv = bi_s[j];
        float A4 = 1.0f, E4 = 0.0f;
        #pragma unroll
        for (int r = 0; r < 4; ++r) {
            int tl = mw * 16 + q * 4 + r;                       // C/D layout: row = q*4 + r
            float la = cjv * sigmoidf_(acc_a[nt][r] + bav);     // log_a <= 0
            float a  = __expf(la);
            float gx = sigmoidf_(acc_x[nt][r] + biv);
            float xv = bf2f(Xs[tl * XS + j]);
            float mult = sqrtf(fmaxf(1.0f - a * a, 0.0f));
            if (t0 + tl == 0) { a = 0.0f; mult = 1.0f; }        // reset at global t=0
            float nxv = xv * gx * mult;
            unsigned short nxb = f2bf(nxv);
            float nxr = bf2f(nxb);
            E4 = fmaf(a, E4, nxr);
            A4 *= a;
            if (FINAL) {
                Ah[tl * XS + j] = f2h_bits(a);
                Xs[tl * XS + j] = nxb;       // in-place: sole reader is this thread (xv above)
            }
        }
        G[(mw * 4 + q) * BW_ + j] = make_float2(A4, E4);
    }
    __syncthreads();

    // level 2: 16-step segment aggregates (all 1024 threads)
    {
        int sg = tid >> 7, jq = tid & 127;
        float A = 1.0f, E = 0.0f;
        #pragma unroll
        for (int i = 0; i < 4; ++i) {
            float2 g = G[(sg * 4 + i) * BW_ + jq];
            E = fmaf(g.x, E, g.y);
            A *= g.x;
        }
        S2[sg * BW_ + jq] = make_float2(A, E);
    }
    __syncthreads();

    if (!FINAL) {
        if (tid < BW_) {
            float At = 1.0f, Et = 0.0f;
            #pragma unroll
            for (int s8 = 0; s8 < NS_; ++s8) {
                float2 v = S2[s8 * BW_ + tid];
                Et = fmaf(v.x, Et, v.y);
                At *= v.x;
            }
            size_t idx = ((size_t)s * NC_ + c) * BW_ + tid;
            aggA[idx] = At;
            aggE[idx] = Et;
        }
    } else {
        if (tid < BW_) {
            float hh = carry[((size_t)s * NC_ + c) * BW_ + tid];
            #pragma unroll
            for (int s8 = 0; s8 < NS_; ++s8) {
                qin[s8 * BW_ + tid] = hh;
                float2 v = S2[s8 * BW_ + tid];
                hh = fmaf(v.x, hh, v.y);
            }
        }
        __syncthreads();
        const int jq = tid & 127;
        const int qq = tid >> 7;
        float hcur = qin[qq * BW_ + jq];
        float* yg = y + ((size_t)b * T_ + t0) * W_ + h * BW_ + jq;
        #pragma unroll 4
        for (int i = 0; i < 16; ++i) {
            int t = qq * 16 + i;
            float a   = h2f(Ah[t * XS + jq]);
            float nxv = bf2f(Xs[t * XS + jq]);
            hcur = fmaf(a, hcur, nxv);
            yg[(size_t)t * W_] = hcur;     // coalesced across jq lanes
        }
    }
}

extern "C" void kernel_launch(void* const* d_in, const int* in_sizes, int n_in,
                              void* d_out, int out_size, void* d_ws, size_t ws_size,
                              hipStream_t stream)
{
    const float* x     = (const float*)d_in[0];
    const float* w_in  = (const float*)d_in[1];
    const float* b_in  = (const float*)d_in[2];
    const float* w_a   = (const float*)d_in[3];
    const float* b_a   = (const float*)d_in[4];
    const float* a_par = (const float*)d_in[5];
    float* y = (float*)d_out;

    char* ws = (char*)d_ws;
    unsigned short* wt_in = (unsigned short*)(ws);
    unsigned short* wt_a  = (unsigned short*)(ws + 262144);
    float* cj    = (float*)(ws + 524288);
    float* aggA  = (float*)(ws + 528384);
    float* aggE  = (float*)(ws + 1576960);
    float* carry = (float*)(ws + 2625536);
    if (ws_size < 3674112) return;

    prep_kernel<<<dim3(128), dim3(256), 0, stream>>>(w_in, w_a, a_par, wt_in, wt_a, cj);
    rg_main<false><<<dim3(2048), dim3(1024), 0, stream>>>(
        x, wt_in, wt_a, b_in, b_a, cj, aggA, aggE, (const float*)nullptr, (float*)nullptr);
    carry_scan<<<dim3(32), dim3(256), 0, stream>>>(aggA, aggE, carry);
    rg_main<true><<<dim3(2048), dim3(1024), 0, stream>>>(
        x, wt_in, wt_a, b_in, b_a, cj, aggA, aggE, carry, y);
}